// Round 1
// baseline (950.727 us; speedup 1.0000x reference)
//
#include <hip/hip_runtime.h>
#include <hip/hip_bf16.h>

#define CIN 256
#define COUT 64

// ---------------- utility ----------------
__global__ void zero_kernel(int* __restrict__ p, int n) {
    int i = blockIdx.x * blockDim.x + threadIdx.x;
    if (i < n) p[i] = 0;
}

// ---------------- degree histogram over dst ----------------
__global__ void hist_kernel(const int* __restrict__ dst, int* __restrict__ cnt, int E) {
    int e = blockIdx.x * blockDim.x + threadIdx.x;
    if (e < E) atomicAdd(&cnt[dst[e]], 1);
}

// ---------------- 2-level exclusive scan ----------------
__global__ __launch_bounds__(1024) void scan_a(const int* __restrict__ cnt,
                                               int* __restrict__ rowptr,
                                               int* __restrict__ bsums, int N) {
    __shared__ int sm[1024];
    int i = blockIdx.x * 1024 + threadIdx.x;
    int v = (i < N) ? cnt[i] : 0;
    sm[threadIdx.x] = v;
    __syncthreads();
    for (int off = 1; off < 1024; off <<= 1) {
        int t = (threadIdx.x >= off) ? sm[threadIdx.x - off] : 0;
        __syncthreads();
        sm[threadIdx.x] += t;
        __syncthreads();
    }
    if (i < N) rowptr[i] = sm[threadIdx.x] - v;  // exclusive (pre block offset)
    if (threadIdx.x == 1023) bsums[blockIdx.x] = sm[1023];
}

__global__ __launch_bounds__(1024) void scan_b(const int* __restrict__ bsums,
                                               int* __restrict__ boffs, int NB) {
    __shared__ int sm[1024];
    int v = (threadIdx.x < NB) ? bsums[threadIdx.x] : 0;
    sm[threadIdx.x] = v;
    __syncthreads();
    for (int off = 1; off < 1024; off <<= 1) {
        int t = (threadIdx.x >= off) ? sm[threadIdx.x - off] : 0;
        __syncthreads();
        sm[threadIdx.x] += t;
        __syncthreads();
    }
    if (threadIdx.x < NB) boffs[threadIdx.x] = sm[threadIdx.x] - v;
}

// add block offsets; compute dinv; repurpose cnt as scatter cursor (zero it)
__global__ void scan_c(int* __restrict__ rowptr, const int* __restrict__ boffs,
                       int* __restrict__ cnt, float* __restrict__ dinv, int N, int E) {
    int i = blockIdx.x * blockDim.x + threadIdx.x;
    if (i < N) {
        rowptr[i] += boffs[i >> 10];
        dinv[i] = rsqrtf((float)(cnt[i] + 1));  // +1 self-loop
        cnt[i] = 0;                             // becomes cursor
    }
    if (i == 0) rowptr[N] = E;
}

// ---------------- scatter edges into CSR (columns = src) ----------------
__global__ void scatter_kernel(const int* __restrict__ src, const int* __restrict__ dst,
                               const int* __restrict__ rowptr, int* __restrict__ cursor,
                               int* __restrict__ col, int E) {
    int e = blockIdx.x * blockDim.x + threadIdx.x;
    if (e < E) {
        int d = dst[e];
        int pos = rowptr[d] + atomicAdd(&cursor[d], 1);
        col[pos] = src[e];
    }
}

// ---------------- h2 = (x @ W) * dinv[row] ----------------
// one wave per 2 rows; lane = output channel; W in LDS (64 KB); x reads wave-uniform
__global__ __launch_bounds__(256) void gemm_kernel(const float* __restrict__ x,
                                                   const float* __restrict__ W,
                                                   const float* __restrict__ dinv,
                                                   float* __restrict__ h2, int N) {
    __shared__ float Ws[CIN * COUT];
    for (int i = threadIdx.x; i < CIN * COUT / 4; i += 256)
        ((float4*)Ws)[i] = ((const float4*)W)[i];
    __syncthreads();

    const int lane = threadIdx.x & 63;
    const int wave = threadIdx.x >> 6;
    const int nwaves = gridDim.x * 4;
    const int npairs = (N + 1) >> 1;
    int gw = __builtin_amdgcn_readfirstlane(blockIdx.x * 4 + wave);

    for (int pr = gw; pr < npairs; pr += nwaves) {
        const int r0 = pr * 2;
        const int r1 = r0 + 1;
        const bool has1 = (r1 < N);
        const float* __restrict__ x0 = x + (size_t)r0 * CIN;
        const float* __restrict__ x1 = x + (size_t)(has1 ? r1 : r0) * CIN;
        float a0 = 0.f, a1 = 0.f;
#pragma unroll 8
        for (int k = 0; k < CIN; ++k) {
            const float w = Ws[k * COUT + lane];  // bank = lane%32 -> 2-way, free
            a0 += x0[k] * w;
            a1 += x1[k] * w;
        }
        h2[(size_t)r0 * COUT + lane] = a0 * dinv[r0];
        if (has1) h2[(size_t)r1 * COUT + lane] = a1 * dinv[r1];
    }
}

// ---------------- pull-gather: one wave per node, lane = channel ----------------
__global__ __launch_bounds__(256) void gather_kernel(const float* __restrict__ h2,
                                                     const int* __restrict__ rowptr,
                                                     const int* __restrict__ col,
                                                     const float* __restrict__ dinv,
                                                     const float* __restrict__ b,
                                                     float* __restrict__ out, int N) {
    const int lane = threadIdx.x & 63;
    const int node = blockIdx.x * 4 + (threadIdx.x >> 6);
    if (node >= N) return;
    const int p0 = rowptr[node];
    const int p1 = rowptr[node + 1];
    float acc = h2[(size_t)node * COUT + lane];  // self-loop term
    for (int p = p0; p < p1; ++p) {
        const int s = col[p];
        acc += h2[(size_t)s * COUT + lane];
    }
    out[(size_t)node * COUT + lane] = acc * dinv[node] + b[lane];
}

// ---------------- launch ----------------
extern "C" void kernel_launch(void* const* d_in, const int* in_sizes, int n_in,
                              void* d_out, int out_size, void* d_ws, size_t ws_size,
                              hipStream_t stream) {
    const float* x = (const float*)d_in[0];
    const int* ei = (const int*)d_in[1];
    const float* W = (const float*)d_in[2];
    const float* b = (const float*)d_in[3];
    float* out = (float*)d_out;

    const int N = in_sizes[0] / CIN;
    const int E = in_sizes[1] / 2;
    const int* src = ei;
    const int* dst = ei + E;
    const int NB = (N + 1023) / 1024;

    // workspace layout (256 B aligned chunks)
    auto align_up = [](size_t v) { return (v + 255) & ~(size_t)255; };
    char* ws = (char*)d_ws;
    size_t off = 0;
    int* cnt = (int*)(ws + off);      off = align_up(off + (size_t)N * 4);        // also cursor
    int* rowptr = (int*)(ws + off);   off = align_up(off + (size_t)(N + 1) * 4);
    float* dinv = (float*)(ws + off); off = align_up(off + (size_t)N * 4);
    int* bsums = (int*)(ws + off);    off = align_up(off + (size_t)NB * 4);
    int* boffs = (int*)(ws + off);    off = align_up(off + (size_t)NB * 4);
    int* col = (int*)(ws + off);      off = align_up(off + (size_t)E * 4);
    float* h2 = (float*)(ws + off);   off = align_up(off + (size_t)N * COUT * 4);
    (void)ws_size;

    // 1. zero degree counters
    zero_kernel<<<(N + 255) / 256, 256, 0, stream>>>(cnt, N);
    // 2. degree histogram
    hist_kernel<<<(E + 255) / 256, 256, 0, stream>>>(dst, cnt, E);
    // 3-5. exclusive scan -> rowptr; dinv; cursor=0
    scan_a<<<NB, 1024, 0, stream>>>(cnt, rowptr, bsums, N);
    scan_b<<<1, 1024, 0, stream>>>(bsums, boffs, NB);
    scan_c<<<(N + 255) / 256, 256, 0, stream>>>(rowptr, boffs, cnt, dinv, N, E);
    // 6. scatter edges into CSR
    scatter_kernel<<<(E + 255) / 256, 256, 0, stream>>>(src, dst, rowptr, cnt, col, E);
    // 7. projection h2 = (x@W)*dinv
    gemm_kernel<<<1024, 256, 0, stream>>>(x, W, dinv, h2, N);
    // 8. pull-gather + bias
    gather_kernel<<<(N + 3) / 4, 256, 0, stream>>>(h2, rowptr, col, dinv, b, out, N);
}

// Round 2
// 589.917 us; speedup vs baseline: 1.6116x; 1.6116x over previous
//
#include <hip/hip_runtime.h>
#include <hip/hip_bf16.h>

#define CIN 256
#define COUT 64
#define WPAD 264  // padded K stride (elements) for transposed W in LDS; 264*2B=528B rows, 16B-aligned

typedef __attribute__((ext_vector_type(8))) short short8;
typedef __attribute__((ext_vector_type(4))) float floatx4;

// ---- fp32 <-> bf16 split helpers (RTN) ----
static __device__ __forceinline__ unsigned short f2bf(float f) {
    unsigned u = __builtin_bit_cast(unsigned, f);
    return (unsigned short)((u + 0x7FFFu + ((u >> 16) & 1u)) >> 16);
}
static __device__ __forceinline__ float bf2f(unsigned short h) {
    unsigned u = ((unsigned)h) << 16;
    return __builtin_bit_cast(float, u);
}

// ---------------- utility ----------------
__global__ void zero_kernel(int* __restrict__ p, int n) {
    int i = blockIdx.x * blockDim.x + threadIdx.x;
    if (i < n) p[i] = 0;
}

// ---------------- degree histogram over dst ----------------
__global__ void hist_kernel(const int* __restrict__ dst, int* __restrict__ cnt, int E) {
    int e = blockIdx.x * blockDim.x + threadIdx.x;
    if (e < E) atomicAdd(&cnt[dst[e]], 1);
}

// ---------------- 2-level exclusive scan ----------------
__global__ __launch_bounds__(1024) void scan_a(const int* __restrict__ cnt,
                                               int* __restrict__ rowptr,
                                               int* __restrict__ bsums, int N) {
    __shared__ int sm[1024];
    int i = blockIdx.x * 1024 + threadIdx.x;
    int v = (i < N) ? cnt[i] : 0;
    sm[threadIdx.x] = v;
    __syncthreads();
    for (int off = 1; off < 1024; off <<= 1) {
        int t = (threadIdx.x >= off) ? sm[threadIdx.x - off] : 0;
        __syncthreads();
        sm[threadIdx.x] += t;
        __syncthreads();
    }
    if (i < N) rowptr[i] = sm[threadIdx.x] - v;  // exclusive (pre block offset)
    if (threadIdx.x == 1023) bsums[blockIdx.x] = sm[1023];
}

__global__ __launch_bounds__(1024) void scan_b(const int* __restrict__ bsums,
                                               int* __restrict__ boffs, int NB) {
    __shared__ int sm[1024];
    int v = (threadIdx.x < NB) ? bsums[threadIdx.x] : 0;
    sm[threadIdx.x] = v;
    __syncthreads();
    for (int off = 1; off < 1024; off <<= 1) {
        int t = (threadIdx.x >= off) ? sm[threadIdx.x - off] : 0;
        __syncthreads();
        sm[threadIdx.x] += t;
        __syncthreads();
    }
    if (threadIdx.x < NB) boffs[threadIdx.x] = sm[threadIdx.x] - v;
}

// add block offsets; compute dinv; repurpose cnt as scatter cursor (zero it)
__global__ void scan_c(int* __restrict__ rowptr, const int* __restrict__ boffs,
                       int* __restrict__ cnt, float* __restrict__ dinv, int N, int E) {
    int i = blockIdx.x * blockDim.x + threadIdx.x;
    if (i < N) {
        rowptr[i] += boffs[i >> 10];
        dinv[i] = rsqrtf((float)(cnt[i] + 1));  // +1 self-loop
        cnt[i] = 0;                             // becomes cursor
    }
    if (i == 0) rowptr[N] = E;
}

// ---------------- scatter edges into CSR (columns = src) ----------------
__global__ void scatter_kernel(const int* __restrict__ src, const int* __restrict__ dst,
                               const int* __restrict__ rowptr, int* __restrict__ cursor,
                               int* __restrict__ col, int E) {
    int e = blockIdx.x * blockDim.x + threadIdx.x;
    if (e < E) {
        int d = dst[e];
        int pos = rowptr[d] + atomicAdd(&cursor[d], 1);
        col[pos] = src[e];
    }
}

// ---------------- h2 = (x @ W) * dinv[row]  via bf16x3 MFMA ----------------
// Block = 512 threads = 8 waves; each wave computes a 16-row x 64-col tile.
// W staged transposed in LDS as (hi, lo) bf16 pair: W_T[col][k], K-stride WPAD.
// A fragments load directly from global: lane m=l&15 -> row, quad q=l>>4 -> k-base q*8.
__global__ __launch_bounds__(512) void gemm_mfma_kernel(const float* __restrict__ x,
                                                        const float* __restrict__ W,
                                                        const float* __restrict__ dinv,
                                                        float* __restrict__ h2, int N) {
    __shared__ unsigned short Whi[COUT * WPAD];
    __shared__ unsigned short Wlo[COUT * WPAD];
    // stage W (row-major [k][c] in global) -> transposed [c][k], split hi/lo
    for (int i = threadIdx.x; i < CIN * COUT; i += 512) {
        int k = i >> 6, c = i & 63;
        float w = W[i];
        unsigned short h = f2bf(w);
        unsigned short l = f2bf(w - bf2f(h));
        Whi[c * WPAD + k] = h;
        Wlo[c * WPAD + k] = l;
    }
    __syncthreads();

    const int lane = threadIdx.x & 63;
    const int wave = threadIdx.x >> 6;
    const int m = lane & 15;   // A row-in-tile / B col-in-tile
    const int q = lane >> 4;   // quad -> k-base q*8 (A/B), row-base q*4 (C/D)
    const int row0 = blockIdx.x * 128 + wave * 16;

    int arow = row0 + m;
    if (arow >= N) arow = N - 1;  // clamp; stores are guarded
    const float* __restrict__ xr = x + (size_t)arow * CIN + q * 8;

    floatx4 acc[4] = {floatx4{0,0,0,0}, floatx4{0,0,0,0}, floatx4{0,0,0,0}, floatx4{0,0,0,0}};

#pragma unroll
    for (int kc = 0; kc < 8; ++kc) {
        floatx4 a0 = *(const floatx4*)(xr + kc * 32);
        floatx4 a1 = *(const floatx4*)(xr + kc * 32 + 4);
        short8 ahi, alo;
#pragma unroll
        for (int j = 0; j < 4; ++j) {
            unsigned short h0 = f2bf(a0[j]);
            ahi[j] = (short)h0;
            alo[j] = (short)f2bf(a0[j] - bf2f(h0));
            unsigned short h1 = f2bf(a1[j]);
            ahi[4 + j] = (short)h1;
            alo[4 + j] = (short)f2bf(a1[j] - bf2f(h1));
        }
        const int kb = kc * 32 + q * 8;
#pragma unroll
        for (int ct = 0; ct < 4; ++ct) {
            const int c = ct * 16 + m;
            short8 bhi = *(const short8*)&Whi[c * WPAD + kb];
            short8 blo = *(const short8*)&Wlo[c * WPAD + kb];
            acc[ct] = __builtin_amdgcn_mfma_f32_16x16x32_bf16(ahi, bhi, acc[ct], 0, 0, 0);
            acc[ct] = __builtin_amdgcn_mfma_f32_16x16x32_bf16(ahi, blo, acc[ct], 0, 0, 0);
            acc[ct] = __builtin_amdgcn_mfma_f32_16x16x32_bf16(alo, bhi, acc[ct], 0, 0, 0);
        }
    }

    // C/D layout: col = lane&15 (= m), row = q*4 + reg
#pragma unroll
    for (int r = 0; r < 4; ++r) {
        const int row = row0 + q * 4 + r;
        if (row < N) {
            const float dv = dinv[row];
            float* __restrict__ op = h2 + (size_t)row * COUT;
#pragma unroll
            for (int ct = 0; ct < 4; ++ct)
                op[ct * 16 + m] = acc[ct][r] * dv;
        }
    }
}

// ---------------- pull-gather: one wave per node, lane = channel ----------------
__global__ __launch_bounds__(256) void gather_kernel(const float* __restrict__ h2,
                                                     const int* __restrict__ rowptr,
                                                     const int* __restrict__ col,
                                                     const float* __restrict__ dinv,
                                                     const float* __restrict__ b,
                                                     float* __restrict__ out, int N) {
    const int lane = threadIdx.x & 63;
    const int node = blockIdx.x * 4 + (threadIdx.x >> 6);
    if (node >= N) return;
    const int p0 = rowptr[node];
    const int p1 = rowptr[node + 1];
    float acc = h2[(size_t)node * COUT + lane];  // self-loop term
    int p = p0;
    // unroll x4: 4 independent gathers in flight (latency-bound on L2/L3)
    for (; p + 3 < p1; p += 4) {
        const int s0 = col[p], s1 = col[p + 1], s2 = col[p + 2], s3 = col[p + 3];
        const float v0 = h2[(size_t)s0 * COUT + lane];
        const float v1 = h2[(size_t)s1 * COUT + lane];
        const float v2 = h2[(size_t)s2 * COUT + lane];
        const float v3 = h2[(size_t)s3 * COUT + lane];
        acc += v0 + v1 + v2 + v3;
    }
    for (; p < p1; ++p)
        acc += h2[(size_t)col[p] * COUT + lane];
    out[(size_t)node * COUT + lane] = acc * dinv[node] + b[lane];
}

// ---------------- launch ----------------
extern "C" void kernel_launch(void* const* d_in, const int* in_sizes, int n_in,
                              void* d_out, int out_size, void* d_ws, size_t ws_size,
                              hipStream_t stream) {
    const float* x = (const float*)d_in[0];
    const int* ei = (const int*)d_in[1];
    const float* W = (const float*)d_in[2];
    const float* b = (const float*)d_in[3];
    float* out = (float*)d_out;

    const int N = in_sizes[0] / CIN;
    const int E = in_sizes[1] / 2;
    const int* src = ei;
    const int* dst = ei + E;
    const int NB = (N + 1023) / 1024;

    // workspace layout (256 B aligned chunks)
    auto align_up = [](size_t v) { return (v + 255) & ~(size_t)255; };
    char* ws = (char*)d_ws;
    size_t off = 0;
    int* cnt = (int*)(ws + off);      off = align_up(off + (size_t)N * 4);        // also cursor
    int* rowptr = (int*)(ws + off);   off = align_up(off + (size_t)(N + 1) * 4);
    float* dinv = (float*)(ws + off); off = align_up(off + (size_t)N * 4);
    int* bsums = (int*)(ws + off);    off = align_up(off + (size_t)NB * 4);
    int* boffs = (int*)(ws + off);    off = align_up(off + (size_t)NB * 4);
    int* col = (int*)(ws + off);      off = align_up(off + (size_t)E * 4);
    float* h2 = (float*)(ws + off);   off = align_up(off + (size_t)N * COUT * 4);
    (void)ws_size;

    // 1. zero degree counters
    zero_kernel<<<(N + 255) / 256, 256, 0, stream>>>(cnt, N);
    // 2. degree histogram
    hist_kernel<<<(E + 255) / 256, 256, 0, stream>>>(dst, cnt, E);
    // 3-5. exclusive scan -> rowptr; dinv; cursor=0
    scan_a<<<NB, 1024, 0, stream>>>(cnt, rowptr, bsums, N);
    scan_b<<<1, 1024, 0, stream>>>(bsums, boffs, NB);
    scan_c<<<(N + 255) / 256, 256, 0, stream>>>(rowptr, boffs, cnt, dinv, N, E);
    // 6. scatter edges into CSR
    scatter_kernel<<<(E + 255) / 256, 256, 0, stream>>>(src, dst, rowptr, cnt, col, E);
    // 7. projection h2 = (x@W)*dinv via bf16x3 MFMA
    gemm_mfma_kernel<<<(N + 127) / 128, 512, 0, stream>>>(x, W, dinv, h2, N);
    // 8. pull-gather + bias
    gather_kernel<<<(N + 3) / 4, 256, 0, stream>>>(h2, rowptr, col, dinv, b, out, N);
}

// Round 3
// 417.704 us; speedup vs baseline: 2.2761x; 1.4123x over previous
//
#include <hip/hip_runtime.h>
#include <hip/hip_bf16.h>

#define CIN 256
#define COUT 64
#define WPAD 264       // padded K stride for transposed W in LDS
#define BSHIFT 9       // nodes per bucket = 512
#define NPB 512        // nodes per bucket
#define NWG 256        // workgroups for binning passes

typedef __attribute__((ext_vector_type(8))) short short8;
typedef __attribute__((ext_vector_type(4))) float floatx4;

// ---- fp32 <-> bf16 split helpers (RTN) ----
static __device__ __forceinline__ unsigned short f2bf(float f) {
    unsigned u = __builtin_bit_cast(unsigned, f);
    return (unsigned short)((u + 0x7FFFu + ((u >> 16) & 1u)) >> 16);
}
static __device__ __forceinline__ float bf2f(unsigned short h) {
    unsigned u = ((unsigned)h) << 16;
    return __builtin_bit_cast(float, u);
}

// ---------------- K1: per-workgroup bucket histogram ----------------
__global__ __launch_bounds__(256) void k1_bucket_hist(const int* __restrict__ dst,
                                                      int* __restrict__ H,
                                                      int E, int chunk, int nbuck) {
    __shared__ int cnt[512];
    for (int i = threadIdx.x; i < nbuck; i += 256) cnt[i] = 0;
    __syncthreads();
    const int g = blockIdx.x;
    const int e0 = g * chunk;
    const int e1 = min(E, e0 + chunk);
    for (int e = e0 + threadIdx.x; e < e1; e += 256)
        atomicAdd(&cnt[dst[e] >> BSHIFT], 1);
    __syncthreads();
    for (int i = threadIdx.x; i < nbuck; i += 256) H[i * NWG + g] = cnt[i];
}

// ---------------- 2-level exclusive scan (over H, bucket-major) ----------------
__global__ __launch_bounds__(1024) void scan_a(const int* __restrict__ in,
                                               int* __restrict__ out,
                                               int* __restrict__ bsums, int n) {
    __shared__ int sm[1024];
    int i = blockIdx.x * 1024 + threadIdx.x;
    int v = (i < n) ? in[i] : 0;
    sm[threadIdx.x] = v;
    __syncthreads();
    for (int off = 1; off < 1024; off <<= 1) {
        int t = (threadIdx.x >= off) ? sm[threadIdx.x - off] : 0;
        __syncthreads();
        sm[threadIdx.x] += t;
        __syncthreads();
    }
    if (i < n) out[i] = sm[threadIdx.x] - v;  // exclusive (pre block offset)
    if (threadIdx.x == 1023) bsums[blockIdx.x] = sm[1023];
}

__global__ __launch_bounds__(1024) void scan_b(const int* __restrict__ bsums,
                                               int* __restrict__ boffs, int NB) {
    __shared__ int sm[1024];
    int v = (threadIdx.x < NB) ? bsums[threadIdx.x] : 0;
    sm[threadIdx.x] = v;
    __syncthreads();
    for (int off = 1; off < 1024; off <<= 1) {
        int t = (threadIdx.x >= off) ? sm[threadIdx.x - off] : 0;
        __syncthreads();
        sm[threadIdx.x] += t;
        __syncthreads();
    }
    if (threadIdx.x < NB) boffs[threadIdx.x] = sm[threadIdx.x] - v;
}

__global__ void add_offsets(int* __restrict__ O, const int* __restrict__ boffs, int n) {
    int i = blockIdx.x * blockDim.x + threadIdx.x;
    if (i < n) O[i] += boffs[i >> 10];
}

// ---------------- K3: binned append of packed (dstlow9 | src17) ----------------
__global__ __launch_bounds__(256) void k3_bin(const int* __restrict__ src,
                                              const int* __restrict__ dst,
                                              const int* __restrict__ O,
                                              int* __restrict__ packed,
                                              int E, int chunk, int nbuck) {
    __shared__ int cur[512];
    const int g = blockIdx.x;
    for (int i = threadIdx.x; i < nbuck; i += 256) cur[i] = O[i * NWG + g];
    __syncthreads();
    const int e0 = g * chunk;
    const int e1 = min(E, e0 + chunk);
    for (int e = e0 + threadIdx.x; e < e1; e += 256) {
        const int d = dst[e];
        const int b = d >> BSHIFT;
        const int pos = atomicAdd(&cur[b], 1);
        packed[pos] = ((d & (NPB - 1)) << 17) | src[e];
    }
}

// ---------------- K4: within-bucket sort -> rowptr, dinv, col ----------------
__global__ __launch_bounds__(512) void k4_local_sort(const int* __restrict__ O,
                                                     const int* __restrict__ packed,
                                                     int* __restrict__ rowptr,
                                                     float* __restrict__ dinv,
                                                     int* __restrict__ col,
                                                     int N, int E, int nbuck) {
    __shared__ int lcnt[NPB];
    __shared__ int s[NPB];
    __shared__ int lpos[NPB];
    const int b = blockIdx.x;
    const int segbeg = O[b * NWG];
    const int segend = (b + 1 < nbuck) ? O[(b + 1) * NWG] : E;
    const int n0 = b << BSHIFT;
    const int ncnt = min(N - n0, NPB);
    const int t = threadIdx.x;

    lcnt[t] = 0;
    __syncthreads();
    for (int e = segbeg + t; e < segend; e += 512)
        atomicAdd(&lcnt[packed[e] >> 17], 1);
    __syncthreads();
    // inclusive scan of lcnt into s
    s[t] = lcnt[t];
    __syncthreads();
    for (int off = 1; off < NPB; off <<= 1) {
        int v = (t >= off) ? s[t - off] : 0;
        __syncthreads();
        s[t] += v;
        __syncthreads();
    }
    const int excl = s[t] - lcnt[t];
    lpos[t] = excl;
    if (t < ncnt) {
        rowptr[n0 + t] = segbeg + excl;
        dinv[n0 + t] = rsqrtf((float)(lcnt[t] + 1));  // +1 self-loop
    }
    if (b == nbuck - 1 && t == 0) rowptr[N] = E;
    __syncthreads();
    for (int e = segbeg + t; e < segend; e += 512) {
        const int p = packed[e];
        const int dl = p >> 17;
        const int pos = segbeg + atomicAdd(&lpos[dl], 1);
        col[pos] = p & 0x1FFFF;
    }
}

// ---------------- h2 = (x @ W) * dinv[row]  via bf16x3 MFMA ----------------
__global__ __launch_bounds__(512) void gemm_mfma_kernel(const float* __restrict__ x,
                                                        const float* __restrict__ W,
                                                        const float* __restrict__ dinv,
                                                        float* __restrict__ h2, int N) {
    __shared__ unsigned short Whi[COUT * WPAD];
    __shared__ unsigned short Wlo[COUT * WPAD];
    for (int i = threadIdx.x; i < CIN * COUT; i += 512) {
        int k = i >> 6, c = i & 63;
        float w = W[i];
        unsigned short h = f2bf(w);
        unsigned short l = f2bf(w - bf2f(h));
        Whi[c * WPAD + k] = h;
        Wlo[c * WPAD + k] = l;
    }
    __syncthreads();

    const int lane = threadIdx.x & 63;
    const int wave = threadIdx.x >> 6;
    const int m = lane & 15;
    const int q = lane >> 4;
    const int row0 = blockIdx.x * 128 + wave * 16;

    int arow = row0 + m;
    if (arow >= N) arow = N - 1;  // clamp; stores are guarded
    const float* __restrict__ xr = x + (size_t)arow * CIN + q * 8;

    floatx4 acc[4] = {floatx4{0,0,0,0}, floatx4{0,0,0,0}, floatx4{0,0,0,0}, floatx4{0,0,0,0}};

#pragma unroll
    for (int kc = 0; kc < 8; ++kc) {
        floatx4 a0 = *(const floatx4*)(xr + kc * 32);
        floatx4 a1 = *(const floatx4*)(xr + kc * 32 + 4);
        short8 ahi, alo;
#pragma unroll
        for (int j = 0; j < 4; ++j) {
            unsigned short h0 = f2bf(a0[j]);
            ahi[j] = (short)h0;
            alo[j] = (short)f2bf(a0[j] - bf2f(h0));
            unsigned short h1 = f2bf(a1[j]);
            ahi[4 + j] = (short)h1;
            alo[4 + j] = (short)f2bf(a1[j] - bf2f(h1));
        }
        const int kb = kc * 32 + q * 8;
#pragma unroll
        for (int ct = 0; ct < 4; ++ct) {
            const int c = ct * 16 + m;
            short8 bhi = *(const short8*)&Whi[c * WPAD + kb];
            short8 blo = *(const short8*)&Wlo[c * WPAD + kb];
            acc[ct] = __builtin_amdgcn_mfma_f32_16x16x32_bf16(ahi, bhi, acc[ct], 0, 0, 0);
            acc[ct] = __builtin_amdgcn_mfma_f32_16x16x32_bf16(ahi, blo, acc[ct], 0, 0, 0);
            acc[ct] = __builtin_amdgcn_mfma_f32_16x16x32_bf16(alo, bhi, acc[ct], 0, 0, 0);
        }
    }

    // C/D layout: col = lane&15 (= m), row = q*4 + reg
#pragma unroll
    for (int r = 0; r < 4; ++r) {
        const int row = row0 + q * 4 + r;
        if (row < N) {
            const float dv = dinv[row];
            float* __restrict__ op = h2 + (size_t)row * COUT;
#pragma unroll
            for (int ct = 0; ct < 4; ++ct)
                op[ct * 16 + m] = acc[ct][r] * dv;
        }
    }
}

// ---------------- pull-gather: one wave per node, lane = channel ----------------
__global__ __launch_bounds__(256) void gather_kernel(const float* __restrict__ h2,
                                                     const int* __restrict__ rowptr,
                                                     const int* __restrict__ col,
                                                     const float* __restrict__ dinv,
                                                     const float* __restrict__ b,
                                                     float* __restrict__ out, int N) {
    const int lane = threadIdx.x & 63;
    const int node = blockIdx.x * 4 + (threadIdx.x >> 6);
    if (node >= N) return;
    const int p0 = rowptr[node];
    const int p1 = rowptr[node + 1];
    float acc = h2[(size_t)node * COUT + lane];  // self-loop term
    int p = p0;
    for (; p + 3 < p1; p += 4) {
        const int s0 = col[p], s1 = col[p + 1], s2 = col[p + 2], s3 = col[p + 3];
        const float v0 = h2[(size_t)s0 * COUT + lane];
        const float v1 = h2[(size_t)s1 * COUT + lane];
        const float v2 = h2[(size_t)s2 * COUT + lane];
        const float v3 = h2[(size_t)s3 * COUT + lane];
        acc += v0 + v1 + v2 + v3;
    }
    for (; p < p1; ++p)
        acc += h2[(size_t)col[p] * COUT + lane];
    out[(size_t)node * COUT + lane] = acc * dinv[node] + b[lane];
}

// ---------------- launch ----------------
extern "C" void kernel_launch(void* const* d_in, const int* in_sizes, int n_in,
                              void* d_out, int out_size, void* d_ws, size_t ws_size,
                              hipStream_t stream) {
    const float* x = (const float*)d_in[0];
    const int* ei = (const int*)d_in[1];
    const float* W = (const float*)d_in[2];
    const float* b = (const float*)d_in[3];
    float* out = (float*)d_out;

    const int N = in_sizes[0] / CIN;
    const int E = in_sizes[1] / 2;
    const int* src = ei;
    const int* dst = ei + E;

    const int nbuck = (N + NPB - 1) >> BSHIFT;        // 196
    const int nH = nbuck * NWG;                        // 50176
    const int chunk = (E + NWG - 1) / NWG;             // 12500
    const int NBs = (nH + 1023) / 1024;                // 49

    // workspace layout (256 B aligned chunks)
    auto align_up = [](size_t v) { return (v + 255) & ~(size_t)255; };
    char* ws = (char*)d_ws;
    size_t off = 0;
    int* H = (int*)(ws + off);        off = align_up(off + (size_t)nH * 4);
    int* O = (int*)(ws + off);        off = align_up(off + (size_t)nH * 4);
    int* bsums = (int*)(ws + off);    off = align_up(off + (size_t)NBs * 4);
    int* boffs = (int*)(ws + off);    off = align_up(off + (size_t)NBs * 4);
    int* rowptr = (int*)(ws + off);   off = align_up(off + (size_t)(N + 1) * 4);
    float* dinv = (float*)(ws + off); off = align_up(off + (size_t)N * 4);
    int* col = (int*)(ws + off);      off = align_up(off + (size_t)E * 4);
    float* h2 = (float*)(ws + off);   off = align_up(off + (size_t)N * COUT * 4);
    // packed aliases h2: K4 finishes reading packed before gemm writes h2 (same stream)
    int* packed = (int*)h2;
    (void)ws_size;

    // 1. per-workgroup bucket histogram
    k1_bucket_hist<<<NWG, 256, 0, stream>>>(dst, H, E, chunk, nbuck);
    // 2-4. exclusive scan of H (bucket-major, wg-minor) -> private ranges O
    scan_a<<<NBs, 1024, 0, stream>>>(H, O, bsums, nH);
    scan_b<<<1, 1024, 0, stream>>>(bsums, boffs, NBs);
    add_offsets<<<(nH + 255) / 256, 256, 0, stream>>>(O, boffs, nH);
    // 5. binned append of packed edges (full-line private-range writes)
    k3_bin<<<NWG, 256, 0, stream>>>(src, dst, O, packed, E, chunk, nbuck);
    // 6. within-bucket sort -> rowptr, dinv, col
    k4_local_sort<<<nbuck, 512, 0, stream>>>(O, packed, rowptr, dinv, col, N, E, nbuck);
    // 7. projection h2 = (x@W)*dinv via bf16x3 MFMA (overwrites packed)
    gemm_mfma_kernel<<<(N + 127) / 128, 512, 0, stream>>>(x, W, dinv, h2, N);
    // 8. pull-gather + bias
    gather_kernel<<<(N + 3) / 4, 256, 0, stream>>>(h2, rowptr, col, dinv, b, out, N);
}

// Round 4
// 386.441 us; speedup vs baseline: 2.4602x; 1.0809x over previous
//
#include <hip/hip_runtime.h>
#include <hip/hip_bf16.h>

#define CIN 256
#define COUT 64
#define WPAD 264       // padded K stride for transposed W in LDS
#define BSHIFT 8       // nodes per bucket = 256
#define NPB 256        // nodes per bucket
#define NWG 256        // workgroups for binning passes

typedef __attribute__((ext_vector_type(8))) short short8;
typedef __attribute__((ext_vector_type(4))) float floatx4;

// ---- fp32 <-> bf16 split helpers (RTN) ----
static __device__ __forceinline__ unsigned short f2bf(float f) {
    unsigned u = __builtin_bit_cast(unsigned, f);
    return (unsigned short)((u + 0x7FFFu + ((u >> 16) & 1u)) >> 16);
}
static __device__ __forceinline__ float bf2f(unsigned short h) {
    unsigned u = ((unsigned)h) << 16;
    return __builtin_bit_cast(float, u);
}

// ---------------- K1: per-workgroup bucket histogram ----------------
__global__ __launch_bounds__(256) void k1_bucket_hist(const int* __restrict__ dst,
                                                      int* __restrict__ H,
                                                      int E, int chunk, int nbuck) {
    __shared__ int cnt[512];
    for (int i = threadIdx.x; i < nbuck; i += 256) cnt[i] = 0;
    __syncthreads();
    const int g = blockIdx.x;
    const int e0 = g * chunk;
    const int e1 = min(E, e0 + chunk);
    for (int e = e0 + threadIdx.x; e < e1; e += 256)
        atomicAdd(&cnt[dst[e] >> BSHIFT], 1);
    __syncthreads();
    for (int i = threadIdx.x; i < nbuck; i += 256) H[i * NWG + g] = cnt[i];
}

// ---------------- 2-level exclusive scan (over H, bucket-major) ----------------
__global__ __launch_bounds__(1024) void scan_a(const int* __restrict__ in,
                                               int* __restrict__ out,
                                               int* __restrict__ bsums, int n) {
    __shared__ int sm[1024];
    int i = blockIdx.x * 1024 + threadIdx.x;
    int v = (i < n) ? in[i] : 0;
    sm[threadIdx.x] = v;
    __syncthreads();
    for (int off = 1; off < 1024; off <<= 1) {
        int t = (threadIdx.x >= off) ? sm[threadIdx.x - off] : 0;
        __syncthreads();
        sm[threadIdx.x] += t;
        __syncthreads();
    }
    if (i < n) out[i] = sm[threadIdx.x] - v;  // exclusive (pre block offset)
    if (threadIdx.x == 1023) bsums[blockIdx.x] = sm[1023];
}

__global__ __launch_bounds__(1024) void scan_b(const int* __restrict__ bsums,
                                               int* __restrict__ boffs, int NB) {
    __shared__ int sm[1024];
    int v = (threadIdx.x < NB) ? bsums[threadIdx.x] : 0;
    sm[threadIdx.x] = v;
    __syncthreads();
    for (int off = 1; off < 1024; off <<= 1) {
        int t = (threadIdx.x >= off) ? sm[threadIdx.x - off] : 0;
        __syncthreads();
        sm[threadIdx.x] += t;
        __syncthreads();
    }
    if (threadIdx.x < NB) boffs[threadIdx.x] = sm[threadIdx.x] - v;
}

// ---------------- K3: binned append of packed (dstlow8 | src17) ----------------
__global__ __launch_bounds__(256) void k3_bin(const int* __restrict__ src,
                                              const int* __restrict__ dst,
                                              const int* __restrict__ O,
                                              const int* __restrict__ boffs,
                                              int* __restrict__ packed,
                                              int E, int chunk, int nbuck) {
    __shared__ int cur[512];
    const int g = blockIdx.x;
    for (int i = threadIdx.x; i < nbuck; i += 256) {
        const int fi = i * NWG + g;
        cur[i] = O[fi] + boffs[fi >> 10];
    }
    __syncthreads();
    const int e0 = g * chunk;
    const int e1 = min(E, e0 + chunk);
    for (int e = e0 + threadIdx.x; e < e1; e += 256) {
        const int d = dst[e];
        const int b = d >> BSHIFT;
        const int pos = atomicAdd(&cur[b], 1);
        packed[pos] = ((d & (NPB - 1)) << 17) | src[e];
    }
}

// ---------------- K4: within-bucket sort -> rowptr, dinv, col ----------------
__global__ __launch_bounds__(256) void k4_local_sort(const int* __restrict__ O,
                                                     const int* __restrict__ boffs,
                                                     const int* __restrict__ packed,
                                                     int* __restrict__ rowptr,
                                                     float* __restrict__ dinv,
                                                     int* __restrict__ col,
                                                     int N, int E, int nbuck) {
    __shared__ int lcnt[NPB];
    __shared__ int s[NPB];
    __shared__ int lpos[NPB];
    const int b = blockIdx.x;
    const int ib = b * NWG;
    const int segbeg = O[ib] + boffs[ib >> 10];
    int segend = E;
    if (b + 1 < nbuck) {
        const int ie = (b + 1) * NWG;
        segend = O[ie] + boffs[ie >> 10];
    }
    const int n0 = b << BSHIFT;
    const int ncnt = min(N - n0, NPB);
    const int t = threadIdx.x;

    lcnt[t] = 0;
    __syncthreads();
    for (int e = segbeg + t; e < segend; e += 256)
        atomicAdd(&lcnt[packed[e] >> 17], 1);
    __syncthreads();
    // inclusive scan of lcnt into s
    s[t] = lcnt[t];
    __syncthreads();
    for (int off = 1; off < NPB; off <<= 1) {
        int v = (t >= off) ? s[t - off] : 0;
        __syncthreads();
        s[t] += v;
        __syncthreads();
    }
    const int excl = s[t] - lcnt[t];
    lpos[t] = excl;
    if (t < ncnt) {
        rowptr[n0 + t] = segbeg + excl;
        dinv[n0 + t] = rsqrtf((float)(lcnt[t] + 1));  // +1 self-loop
    }
    if (b == nbuck - 1 && t == 0) rowptr[N] = E;
    __syncthreads();
    for (int e = segbeg + t; e < segend; e += 256) {
        const int p = packed[e];
        const int dl = p >> 17;
        const int pos = segbeg + atomicAdd(&lpos[dl], 1);
        col[pos] = p & 0x1FFFF;
    }
}

// ---------------- h2 = bf16((x @ W) * dinv[row])  via bf16x3 MFMA ----------------
__global__ __launch_bounds__(512) void gemm_mfma_kernel(const float* __restrict__ x,
                                                        const float* __restrict__ W,
                                                        const float* __restrict__ dinv,
                                                        unsigned short* __restrict__ h2,
                                                        int N) {
    __shared__ unsigned short Whi[COUT * WPAD];
    __shared__ unsigned short Wlo[COUT * WPAD];
    for (int i = threadIdx.x; i < CIN * COUT; i += 512) {
        int k = i >> 6, c = i & 63;
        float w = W[i];
        unsigned short h = f2bf(w);
        unsigned short l = f2bf(w - bf2f(h));
        Whi[c * WPAD + k] = h;
        Wlo[c * WPAD + k] = l;
    }
    __syncthreads();

    const int lane = threadIdx.x & 63;
    const int wave = threadIdx.x >> 6;
    const int m = lane & 15;
    const int q = lane >> 4;
    const int row0 = blockIdx.x * 128 + wave * 16;

    int arow = row0 + m;
    if (arow >= N) arow = N - 1;  // clamp; stores are guarded
    const float* __restrict__ xr = x + (size_t)arow * CIN + q * 8;

    floatx4 acc[4] = {floatx4{0,0,0,0}, floatx4{0,0,0,0}, floatx4{0,0,0,0}, floatx4{0,0,0,0}};

#pragma unroll
    for (int kc = 0; kc < 8; ++kc) {
        floatx4 a0 = *(const floatx4*)(xr + kc * 32);
        floatx4 a1 = *(const floatx4*)(xr + kc * 32 + 4);
        short8 ahi, alo;
#pragma unroll
        for (int j = 0; j < 4; ++j) {
            unsigned short h0 = f2bf(a0[j]);
            ahi[j] = (short)h0;
            alo[j] = (short)f2bf(a0[j] - bf2f(h0));
            unsigned short h1 = f2bf(a1[j]);
            ahi[4 + j] = (short)h1;
            alo[4 + j] = (short)f2bf(a1[j] - bf2f(h1));
        }
        const int kb = kc * 32 + q * 8;
#pragma unroll
        for (int ct = 0; ct < 4; ++ct) {
            const int c = ct * 16 + m;
            short8 bhi = *(const short8*)&Whi[c * WPAD + kb];
            short8 blo = *(const short8*)&Wlo[c * WPAD + kb];
            acc[ct] = __builtin_amdgcn_mfma_f32_16x16x32_bf16(ahi, bhi, acc[ct], 0, 0, 0);
            acc[ct] = __builtin_amdgcn_mfma_f32_16x16x32_bf16(ahi, blo, acc[ct], 0, 0, 0);
            acc[ct] = __builtin_amdgcn_mfma_f32_16x16x32_bf16(alo, bhi, acc[ct], 0, 0, 0);
        }
    }

    // C/D layout: col = lane&15 (= m), row = q*4 + reg
#pragma unroll
    for (int r = 0; r < 4; ++r) {
        const int row = row0 + q * 4 + r;
        if (row < N) {
            const float dv = dinv[row];
            unsigned short* __restrict__ op = h2 + (size_t)row * COUT;
#pragma unroll
            for (int ct = 0; ct < 4; ++ct)
                op[ct * 16 + m] = f2bf(acc[ct][r] * dv);
        }
    }
}

// ---------------- pull-gather: one wave per node, lane = channel ----------------
__global__ __launch_bounds__(256) void gather_kernel(const unsigned short* __restrict__ h2,
                                                     const int* __restrict__ rowptr,
                                                     const int* __restrict__ col,
                                                     const float* __restrict__ dinv,
                                                     const float* __restrict__ b,
                                                     float* __restrict__ out, int N) {
    const int lane = threadIdx.x & 63;
    const int node = blockIdx.x * 4 + (threadIdx.x >> 6);
    if (node >= N) return;
    const int p0 = rowptr[node];
    const int p1 = rowptr[node + 1];
    float acc = bf2f(h2[(size_t)node * COUT + lane]);  // self-loop term
    int p = p0;
    // unroll x8: 8 independent gathers in flight (fabric-BW/latency-bound)
    for (; p + 7 < p1; p += 8) {
        float v0 = bf2f(h2[(size_t)col[p] * COUT + lane]);
        float v1 = bf2f(h2[(size_t)col[p + 1] * COUT + lane]);
        float v2 = bf2f(h2[(size_t)col[p + 2] * COUT + lane]);
        float v3 = bf2f(h2[(size_t)col[p + 3] * COUT + lane]);
        float v4 = bf2f(h2[(size_t)col[p + 4] * COUT + lane]);
        float v5 = bf2f(h2[(size_t)col[p + 5] * COUT + lane]);
        float v6 = bf2f(h2[(size_t)col[p + 6] * COUT + lane]);
        float v7 = bf2f(h2[(size_t)col[p + 7] * COUT + lane]);
        acc += ((v0 + v1) + (v2 + v3)) + ((v4 + v5) + (v6 + v7));
    }
    for (; p < p1; ++p)
        acc += bf2f(h2[(size_t)col[p] * COUT + lane]);
    out[(size_t)node * COUT + lane] = acc * dinv[node] + b[lane];
}

// ---------------- launch ----------------
extern "C" void kernel_launch(void* const* d_in, const int* in_sizes, int n_in,
                              void* d_out, int out_size, void* d_ws, size_t ws_size,
                              hipStream_t stream) {
    const float* x = (const float*)d_in[0];
    const int* ei = (const int*)d_in[1];
    const float* W = (const float*)d_in[2];
    const float* b = (const float*)d_in[3];
    float* out = (float*)d_out;

    const int N = in_sizes[0] / CIN;
    const int E = in_sizes[1] / 2;
    const int* src = ei;
    const int* dst = ei + E;

    const int nbuck = (N + NPB - 1) >> BSHIFT;        // 391
    const int nH = nbuck * NWG;                        // 100096
    const int chunk = (E + NWG - 1) / NWG;             // 12500
    const int NBs = (nH + 1023) / 1024;                // 98

    // workspace layout (256 B aligned chunks)
    auto align_up = [](size_t v) { return (v + 255) & ~(size_t)255; };
    char* ws = (char*)d_ws;
    size_t off = 0;
    int* H = (int*)(ws + off);        off = align_up(off + (size_t)nH * 4);
    int* O = (int*)(ws + off);        off = align_up(off + (size_t)nH * 4);
    int* bsums = (int*)(ws + off);    off = align_up(off + (size_t)NBs * 4);
    int* boffs = (int*)(ws + off);    off = align_up(off + (size_t)NBs * 4);
    int* rowptr = (int*)(ws + off);   off = align_up(off + (size_t)(N + 1) * 4);
    float* dinv = (float*)(ws + off); off = align_up(off + (size_t)N * 4);
    int* col = (int*)(ws + off);      off = align_up(off + (size_t)E * 4);
    unsigned short* h2 = (unsigned short*)(ws + off);
    off = align_up(off + (size_t)N * COUT * 2);
    // packed aliases h2 region is NOT possible anymore (h2 is 12.8MB == E*4B);
    // keep packed separate to stay safe.
    int* packed = (int*)(ws + off);   off = align_up(off + (size_t)E * 4);
    (void)ws_size;

    // 1. per-workgroup bucket histogram
    k1_bucket_hist<<<NWG, 256, 0, stream>>>(dst, H, E, chunk, nbuck);
    // 2-3. exclusive scan of H (bucket-major, wg-minor) -> private ranges O (pre-offset)
    scan_a<<<NBs, 1024, 0, stream>>>(H, O, bsums, nH);
    scan_b<<<1, 1024, 0, stream>>>(bsums, boffs, NBs);
    // 4. binned append of packed edges (adds boffs on the fly)
    k3_bin<<<NWG, 256, 0, stream>>>(src, dst, O, boffs, packed, E, chunk, nbuck);
    // 5. within-bucket sort -> rowptr, dinv, col
    k4_local_sort<<<nbuck, 256, 0, stream>>>(O, boffs, packed, rowptr, dinv, col, N, E, nbuck);
    // 6. projection h2 = bf16((x@W)*dinv) via bf16x3 MFMA
    gemm_mfma_kernel<<<(N + 127) / 128, 512, 0, stream>>>(x, W, dinv, h2, N);
    // 7. pull-gather + bias
    gather_kernel<<<(N + 3) / 4, 256, 0, stream>>>(h2, rowptr, col, dinv, b, out, N);
}